// Round 13
// baseline (277.546 us; speedup 1.0000x reference)
//
#include <hip/hip_runtime.h>
#include <hip/hip_fp16.h>
#include <math.h>

typedef __attribute__((ext_vector_type(8))) short short8;
typedef __attribute__((ext_vector_type(4))) float floatx4;
typedef __attribute__((ext_vector_type(2))) float float2v;

__device__ __forceinline__ unsigned short f2bf(float f){
  unsigned int x = __float_as_uint(f);
  unsigned int r = x + 0x7fff + ((x >> 16) & 1);   // RNE
  return (unsigned short)(r >> 16);
}
__device__ __forceinline__ unsigned char f2fp8(float v){
  int pk = __builtin_amdgcn_cvt_pk_fp8_f32(v, 0.f, 0, false);
  return (unsigned char)(pk & 0xff);
}
__device__ __forceinline__ float wsumf(float v){
#pragma unroll
  for (int o = 32; o; o >>= 1) v += __shfl_xor(v, o, 64);
  return v;
}

// ---------------------------------------------------------------- count: 8 XCD-local banks (bank = blockIdx&7)
__global__ __launch_bounds__(256) void k_count(const int* __restrict__ dst,
    const float* __restrict__ eattr, unsigned long long* __restrict__ degp,
    unsigned char* __restrict__ rank, int E, int N){
  int e = blockIdx.x * 256 + threadIdx.x;
  if (e >= E) return;
  int b = blockIdx.x & 7;
  int d = dst[e];
  unsigned long long add = (1ull << 40) |
      (unsigned long long)(eattr[e] * 16777216.0f);
  unsigned long long old = atomicAdd(&degp[(size_t)b * N + d], add);
  rank[e] = (unsigned char)(old >> 40);
}

// ---------------------------------------------------------------- scan1: block-local exclusive + block sums
__global__ __launch_bounds__(256) void k_scan1(const unsigned long long* __restrict__ degp,
    int* __restrict__ row_ptr, int* __restrict__ bsum, int n){
  __shared__ int sm[2][256];
  int tid = threadIdx.x, gid = blockIdx.x * 256 + tid;
  int v = 0;
  if (gid < n){
#pragma unroll
    for (int b = 0; b < 8; b++) v += (int)(degp[(size_t)b * n + gid] >> 40);
  }
  sm[0][tid] = v; __syncthreads();
  int pin = 0;
  for (int off = 1; off < 256; off <<= 1){
    int t = sm[pin][tid];
    if (tid >= off) t += sm[pin][tid - off];
    sm[pin ^ 1][tid] = t; pin ^= 1; __syncthreads();
  }
  int incl = sm[pin][tid];
  if (gid < n) row_ptr[gid] = incl - v;
  if (tid == 255) bsum[blockIdx.x] = incl;
}

// ---------------------------------------------------------------- scan3 (scan2 folded in): block offset by reduction
__global__ __launch_bounds__(256) void k_scan3(int* __restrict__ row_ptr,
    const int* __restrict__ bsum, const unsigned long long* __restrict__ degp,
    float* __restrict__ lattr, int* __restrict__ base, int n, int E){
  int tid = threadIdx.x;
  int partial = (tid < (int)blockIdx.x) ? bsum[tid] : 0;   // nb <= 256
#pragma unroll
  for (int o = 32; o; o >>= 1) partial += __shfl_xor(partial, o, 64);
  __shared__ int ws[4];
  if ((tid & 63) == 0) ws[tid >> 6] = partial;
  __syncthreads();
  int blockOfs = ws[0] + ws[1] + ws[2] + ws[3];
  int gid = blockIdx.x * 256 + tid;
  if (gid >= n) return;
  int rp = row_ptr[gid] + blockOfs;
  row_ptr[gid] = rp;
  const unsigned long long M40 = (1ull << 40) - 1;
  int cum = 0; float s = 0.f;
  int bb[8];
#pragma unroll
  for (int b = 0; b < 8; b++){
    unsigned long long p = degp[(size_t)b * n + gid];
    bb[b] = rp + cum;
    cum += (int)(p >> 40);
    s += (float)(p & M40);
  }
  lattr[gid] = (s * (1.0f / 16777216.0f)) / fmaxf((float)cum, 1.0f);
  int4* bp = (int4*)(base + (size_t)gid * 8);
  bp[0] = make_int4(bb[0], bb[1], bb[2], bb[3]);
  bp[1] = make_int4(bb[4], bb[5], bb[6], bb[7]);
  if (gid == 0) row_ptr[n] = E;
}

// ---------------------------------------------------------------- scatter: CSR-ordered packed {src:16b, ea:fp16}
__global__ __launch_bounds__(256) void k_scatter(const int* __restrict__ src,
    const int* __restrict__ dst, const float* __restrict__ eattr,
    const unsigned char* __restrict__ rank, const int* __restrict__ base,
    unsigned* __restrict__ csrp, int E){
  int e = blockIdx.x * 256 + threadIdx.x;
  if (e >= E) return;
  int b = blockIdx.x & 7;
  int d = dst[e];
  int pos = base[(size_t)d * 8 + b] + (int)rank[e];
  unsigned u = (unsigned)src[e] |
      ((unsigned)__half_as_ushort(__float2half_rn(eattr[e])) << 16);
  csrp[pos] = u;
}

// ---------------------------------------------------------------- prep: B1 tiles (17), w2vT[4][256], ce + c1/c2
__global__ void k_prep(const float* __restrict__ W1, const float* __restrict__ as1,
    const float* __restrict__ ad1, const float* __restrict__ W2,
    const float* __restrict__ as2, const float* __restrict__ ad2,
    const float* __restrict__ We1, const float* __restrict__ ae1,
    const float* __restrict__ We2, const float* __restrict__ ae2,
    const float* __restrict__ b2, const float* __restrict__ Wlin,
    unsigned short* __restrict__ W1p, float* __restrict__ w2vT,
    float* __restrict__ ce){
  int b = blockIdx.x, lane = threadIdx.x;
  if (b < 68){
    int nt = b >> 2, kc = b & 3;
    int col = lane & 15, krow = kc * 32 + (lane >> 4) * 8;
    unsigned short tmp[8];
    if (nt < 16){
#pragma unroll
      for (int j = 0; j < 8; j++) tmp[j] = f2bf(W1[(size_t)(krow + j) * 256 + nt * 16 + col]);
    } else {
#pragma unroll
      for (int j = 0; j < 8; j++){
        float v = 0.f;
        if (col < 8){
          const float* av = (col < 4) ? as1 : ad1;
          int h = col & 3;
          for (int c = 0; c < 64; c++)
            v += W1[(size_t)(krow + j) * 256 + h * 64 + c] * av[h * 64 + c];
        }
        tmp[j] = f2bf(v);
      }
    }
    unsigned short* dstp = W1p + (((size_t)nt * 4 + kc) * 64 + lane) * 8;
    *(ushort4*)(dstp)     = make_ushort4(tmp[0], tmp[1], tmp[2], tmp[3]);
    *(ushort4*)(dstp + 4) = make_ushort4(tmp[4], tmp[5], tmp[6], tmp[7]);
  } else if (b < 72){
    int k = (b - 68) * 64 + lane;
    float4 a = make_float4(0.f, 0.f, 0.f, 0.f);
    for (int c = 0; c < 64; c++){
      float wv = W2[(size_t)k * 64 + c];
      a.x += wv * as2[c];
      a.y += wv * ad2[c];
      a.z += wv * Wlin[c];
      a.w += wv * Wlin[64 + c];
    }
    w2vT[k]       = a.x;
    w2vT[256 + k] = a.y;
    w2vT[512 + k] = a.z;
    w2vT[768 + k] = a.w;
  } else {
    float p0 = We1[lane]       * ae1[lane];
    float p1 = We1[64 + lane]  * ae1[64 + lane];
    float p2 = We1[128 + lane] * ae1[128 + lane];
    float p3 = We1[192 + lane] * ae1[192 + lane];
    float p4 = We2[lane]       * ae2[lane];
    float c1 = b2[lane] * Wlin[lane];
    float c2 = b2[lane] * Wlin[64 + lane];
    p0 = wsumf(p0); p1 = wsumf(p1); p2 = wsumf(p2); p3 = wsumf(p3); p4 = wsumf(p4);
    c1 = wsumf(c1); c2 = wsumf(c2);
    if (lane == 0){
      ce[0] = p0; ce[1] = p1; ce[2] = p2; ce[3] = p3; ce[4] = p4;
      ce[5] = c1; ce[6] = c2;
    }
  }
}

// ---------------------------------------------------------------- GEMM1: fp32 A, 16 LDS tiles + reg score tile
__global__ __launch_bounds__(256) void k_gemm1_att(const float* __restrict__ A,
    const unsigned short* __restrict__ Bp, unsigned char* __restrict__ h1f8,
    float* __restrict__ asrc, float* __restrict__ adst, int M){
  constexpr int K = 128, NKC = 4;
  __shared__ unsigned short Bs[256 * K];
  {
    const uint4* srcp = (const uint4*)Bp;
    uint4* dstp = (uint4*)Bs;
    for (int i = threadIdx.x; i < 4096; i += 256) dstp[i] = srcp[i];
  }
  __syncthreads();
  int wave = threadIdx.x >> 6, lane = threadIdx.x & 63;
  int quad = lane >> 4, col = lane & 15;
  int r0 = (blockIdx.x * 4 + wave) * 16;
  int rowc = min(r0 + col, M - 1);
  short8 af[NKC], sf[NKC];
#pragma unroll
  for (int kc = 0; kc < NKC; kc++){
    float4 a0 = *(const float4*)(A + (size_t)rowc * K + kc * 32 + quad * 8);
    float4 a1 = *(const float4*)(A + (size_t)rowc * K + kc * 32 + quad * 8 + 4);
    short8 t;
    t[0] = (short)f2bf(a0.x); t[1] = (short)f2bf(a0.y);
    t[2] = (short)f2bf(a0.z); t[3] = (short)f2bf(a0.w);
    t[4] = (short)f2bf(a1.x); t[5] = (short)f2bf(a1.y);
    t[6] = (short)f2bf(a1.z); t[7] = (short)f2bf(a1.w);
    af[kc] = t;
    sf[kc] = *(const short8*)(Bp + (((size_t)16 * 4 + kc) * 64 + lane) * 8);
  }
  floatx4 acc[17];
#pragma unroll
  for (int nt = 0; nt < 17; nt++) acc[nt] = (floatx4){0.f, 0.f, 0.f, 0.f};
#pragma unroll
  for (int kc = 0; kc < NKC; kc++){
#pragma unroll
    for (int nt = 0; nt < 16; nt++){
      short8 bfv = *(const short8*)(&Bs[((nt * NKC + kc) * 64 + lane) * 8]);
      acc[nt] = __builtin_amdgcn_mfma_f32_16x16x32_bf16(af[kc], bfv, acc[nt], 0, 0, 0);
    }
    acc[16] = __builtin_amdgcn_mfma_f32_16x16x32_bf16(af[kc], sf[kc], acc[16], 0, 0, 0);
  }
#pragma unroll
  for (int nt = 0; nt < 16; nt++){
#pragma unroll
    for (int i = 0; i < 4; i++){
      int r = r0 + quad * 4 + i;
      if (r < M) h1f8[(size_t)r * 256 + nt * 16 + col] = f2fp8(acc[nt][i]);
    }
  }
#pragma unroll
  for (int i = 0; i < 4; i++){
    int r = r0 + quad * 4 + i;
    if (r < M){
      float v = acc[16][i];
      if (col < 4)      asrc[(size_t)r * 4 + col] = v;
      else if (col < 8) adst[(size_t)r * 4 + (col - 4)] = v;
    }
  }
}

// ---------------------------------------------------------------- GAT layer 1 (fused L2 projection, coalesced epilogue)
__global__ __launch_bounds__(256) void k_gat1(
    const int* __restrict__ row_ptr, const unsigned* __restrict__ csrp,
    const float* __restrict__ lattr,
    const float* __restrict__ a_src, const float* __restrict__ a_dst,
    const float* __restrict__ ce, const unsigned char* __restrict__ hpre,
    const float* __restrict__ bias, const float* __restrict__ w2vT,
    float4* __restrict__ upd, int n){
  int node = blockIdx.x * 4 + (threadIdx.x >> 6);
  if (node >= n) return;
  int lane = threadIdx.x & 63;
  int q = lane >> 4, lsub = lane & 15, hq = lsub >> 2;
  int start = row_ptr[node], deg = row_ptr[node + 1] - start;
  float4 as4 = *(const float4*)(a_src + (size_t)node * 4);
  float4 ad4 = *(const float4*)(a_dst + (size_t)node * 4);
  float4 ce4 = *(const float4*)ce;
  float la = lattr[node];
  // loop-invariant: projection weights + bias (coalesced lane*64B / lane*... reads)
  float4 wv4[4], bb4[4];
#pragma unroll
  for (int j = 0; j < 4; j++){
    wv4[j] = *(const float4*)(w2vT + (size_t)lane * 16 + j * 4);
    bb4[j] = *(const float4*)(bias + lsub * 16 + j * 4);
  }
  float asvh = hq == 0 ? as4.x : hq == 1 ? as4.y : hq == 2 ? as4.z : as4.w;
  float advh = hq == 0 ? ad4.x : hq == 1 ? ad4.y : hq == 2 ? ad4.z : ad4.w;
  float ceh  = hq == 0 ? ce4.x : hq == 1 ? ce4.y : hq == 2 ? ce4.z : ce4.w;
  float2v acc2[8];
#pragma unroll
  for (int k = 0; k < 8; k++) acc2[k] = (float2v){0.f, 0.f};
  float dn = 0.f;
  if (q == 0){                                    // self-loop handled once
    float aself = asvh + advh + la * ceh;
    aself = aself > 0.f ? aself : 0.2f * aself;
    float wself = __expf(aself);
    dn = wself;
    uint4 u = *(const uint4*)(hpre + (size_t)node * 256 + lsub * 16);
    float2v w2 = (float2v){wself, wself};
    unsigned uu[4] = {u.x, u.y, u.z, u.w};
#pragma unroll
    for (int j = 0; j < 4; j++){
      acc2[2 * j]     = w2 * __builtin_amdgcn_cvt_pk_f32_fp8((int)uu[j], false);
      acc2[2 * j + 1] = w2 * __builtin_amdgcn_cvt_pk_f32_fp8((int)uu[j], true);
    }
  }
  for (int e = q; e < deg; e += 8){               // 2 edges per iter per quarter
    bool vB = (e + 4) < deg;
    unsigned uA_ = csrp[start + e];
    unsigned uB_ = csrp[start + (vB ? e + 4 : e)];
    int sA = (int)(uA_ & 0xffffu), sB = (int)(uB_ & 0xffffu);
    float eaA = __half2float(__ushort_as_half((unsigned short)(uA_ >> 16)));
    float eaB = __half2float(__ushort_as_half((unsigned short)(uB_ >> 16)));
    float aA = a_src[(size_t)sA * 4 + hq] + advh + eaA * ceh;
    aA = aA > 0.f ? aA : 0.2f * aA;
    float wA = __expf(aA);
    float aB = a_src[(size_t)sB * 4 + hq] + advh + eaB * ceh;
    aB = aB > 0.f ? aB : 0.2f * aB;
    float wB = vB ? __expf(aB) : 0.f;
    uint4 uA = *(const uint4*)(hpre + (size_t)sA * 256 + lsub * 16);
    uint4 uB = *(const uint4*)(hpre + (size_t)sB * 256 + lsub * 16);
    dn += wA + wB;
    float2v wA2 = (float2v){wA, wA}, wB2 = (float2v){wB, wB};
    unsigned ua[4] = {uA.x, uA.y, uA.z, uA.w};
    unsigned ub[4] = {uB.x, uB.y, uB.z, uB.w};
#pragma unroll
    for (int j = 0; j < 4; j++){
      acc2[2 * j]     += wA2 * __builtin_amdgcn_cvt_pk_f32_fp8((int)ua[j], false);
      acc2[2 * j + 1] += wA2 * __builtin_amdgcn_cvt_pk_f32_fp8((int)ua[j], true);
      acc2[2 * j]     += wB2 * __builtin_amdgcn_cvt_pk_f32_fp8((int)ub[j], false);
      acc2[2 * j + 1] += wB2 * __builtin_amdgcn_cvt_pk_f32_fp8((int)ub[j], true);
    }
  }
  dn += __shfl_xor(dn, 16, 64);
  dn += __shfl_xor(dn, 32, 64);
#pragma unroll
  for (int k = 0; k < 8; k++){
    acc2[k].x += __shfl_xor(acc2[k].x, 16, 64);
    acc2[k].x += __shfl_xor(acc2[k].x, 32, 64);
    acc2[k].y += __shfl_xor(acc2[k].y, 16, 64);
    acc2[k].y += __shfl_xor(acc2[k].y, 32, 64);
  }
  // All-lane epilogue: quarter q computes output component q of upd[node].
  {
    float inv = 1.f / dn;
    float d = 0.f;
#pragma unroll
    for (int j = 0; j < 4; j++){
      float bbv[4] = {bb4[j].x, bb4[j].y, bb4[j].z, bb4[j].w};
      float wvv[4] = {wv4[j].x, wv4[j].y, wv4[j].z, wv4[j].w};
#pragma unroll
      for (int t = 0; t < 4; t++){
        int k = j * 4 + t;
        float av = (k & 1) ? acc2[k >> 1].y : acc2[k >> 1].x;
        float v = av * inv + bbv[t];
        v = v > 0.f ? v : (__expf(v) - 1.f);    // elu(h1)
        d += v * wvv[t];
      }
    }
#pragma unroll
    for (int o = 1; o < 16; o <<= 1) d += __shfl_xor(d, o, 64);
    if (lsub == 0) ((float*)&upd[node])[q] = d;
  }
}

// ---------------------------------------------------------------- GAT layer 2: scalar-only (8 lanes per node)
__global__ __launch_bounds__(256) void k_gat2(
    const int* __restrict__ row_ptr, const unsigned* __restrict__ csrp,
    const float* __restrict__ lattr, const float4* __restrict__ upd,
    const float* __restrict__ ce,
    float* __restrict__ s1v, float* __restrict__ s2v, int n){
  int node = blockIdx.x * 32 + (threadIdx.x >> 3);
  if (node >= n) return;
  int lane8 = threadIdx.x & 7;
  int start = row_ptr[node], deg = row_ptr[node + 1] - start;
  float4 own = upd[node];
  float ad = own.y, c = ce[4];
  float t1 = 0.f, t2 = 0.f, dn = 0.f;
  if (lane8 == 0){
    float a = own.x + ad + lattr[node] * c;
    a = a > 0.f ? a : 0.2f * a;
    float w = __expf(a);
    dn = w; t1 = w * own.z; t2 = w * own.w;
  }
  for (int e = lane8; e < deg; e += 8){
    unsigned u = csrp[start + e];
    int s = (int)(u & 0xffffu);
    float ea = __half2float(__ushort_as_half((unsigned short)(u >> 16)));
    float4 o = upd[s];
    float a = o.x + ad + ea * c;
    a = a > 0.f ? a : 0.2f * a;
    float w = __expf(a);
    dn += w; t1 += w * o.z; t2 += w * o.w;
  }
#pragma unroll
  for (int o = 1; o < 8; o <<= 1){
    dn += __shfl_xor(dn, o, 64);
    t1 += __shfl_xor(t1, o, 64);
    t2 += __shfl_xor(t2, o, 64);
  }
  if (lane8 == 0){
    float inv = 1.f / dn;
    s1v[node] = t1 * inv + ce[5];
    s2v[node] = t2 * inv + ce[6];
  }
}

// ---------------------------------------------------------------- pair head
__global__ __launch_bounds__(256) void k_pairs(const int* __restrict__ pairs,
    const float* __restrict__ s1v, const float* __restrict__ s2v,
    const float* __restrict__ blin, float* __restrict__ out, int P){
  int p = blockIdx.x * 256 + threadIdx.x;
  if (p >= P) return;
  int i = pairs[2 * p], j = pairs[2 * p + 1];
  float x = s1v[i] + s2v[j] + blin[0];
  out[p] = 1.f / (1.f + __expf(-x));
}

// ---------------------------------------------------------------- launch
extern "C" void kernel_launch(void* const* d_in, const int* in_sizes, int n_in,
                              void* d_out, int out_size, void* d_ws, size_t ws_size,
                              hipStream_t stream) {
  const float* x     = (const float*)d_in[0];
  const int*   esrc  = (const int*)  d_in[1];
  const int*   edst  = (const int*)  d_in[2];
  const float* eattr = (const float*)d_in[3];
  const int*   pairs = (const int*)  d_in[4];
  const float* W1    = (const float*)d_in[5];
  const float* We1   = (const float*)d_in[6];
  const float* as1   = (const float*)d_in[7];
  const float* ad1   = (const float*)d_in[8];
  const float* ae1   = (const float*)d_in[9];
  const float* b1    = (const float*)d_in[10];
  const float* W2    = (const float*)d_in[11];
  const float* We2   = (const float*)d_in[12];
  const float* as2   = (const float*)d_in[13];
  const float* ad2   = (const float*)d_in[14];
  const float* ae2   = (const float*)d_in[15];
  const float* b2    = (const float*)d_in[16];
  const float* Wlin  = (const float*)d_in[17];
  const float* blin  = (const float*)d_in[18];
  float* out = (float*)d_out;

  const int N = in_sizes[0] / 128;
  const int E = in_sizes[1];
  const int P = in_sizes[4] / 2;

  char* w = (char*)d_ws;
  size_t off = 0;
  auto alloc = [&](size_t bytes) -> size_t {
    size_t r = off; off = (off + bytes + 255) & ~(size_t)255; return r;
  };
  size_t o_degp   = alloc((size_t)N * 64);   // 8 banks of u64
  size_t zero_end = off;
  size_t o_rank   = alloc((size_t)E);        // uint8 rank
  size_t o_rowptr = alloc((size_t)(N + 1) * 4);
  size_t o_bsum   = alloc(1024);
  size_t o_lattr  = alloc((size_t)N * 4);
  size_t o_base   = alloc((size_t)N * 32);
  size_t o_csr    = alloc((size_t)E * 4);    // packed {src:16, ea:fp16}
  size_t o_asrc1  = alloc((size_t)N * 16);
  size_t o_adst1  = alloc((size_t)N * 16);
  size_t o_upd    = alloc((size_t)N * 16);
  size_t o_ce     = alloc(64);
  size_t o_s1     = alloc((size_t)N * 4);
  size_t o_s2     = alloc((size_t)N * 4);
  size_t o_W1p    = alloc((size_t)17 * 4 * 64 * 8 * 2);
  size_t o_w2v    = alloc(256 * 16);         // w2vT[4][256] floats
  size_t o_h1f8   = alloc((size_t)N * 256);
  (void)ws_size;

  unsigned long long* degp = (unsigned long long*)(w + o_degp);
  unsigned char* rank = (unsigned char*)(w + o_rank);
  int*   rowptr = (int*)  (w + o_rowptr);
  int*   bsum   = (int*)  (w + o_bsum);
  float* lattr  = (float*)(w + o_lattr);
  int*   base   = (int*)  (w + o_base);
  unsigned* csrp = (unsigned*)(w + o_csr);
  float* asrc1  = (float*)(w + o_asrc1);
  float* adst1  = (float*)(w + o_adst1);
  float4* upd   = (float4*)(w + o_upd);
  float* ce     = (float*)(w + o_ce);
  float* s1v    = (float*)(w + o_s1);
  float* s2v    = (float*)(w + o_s2);
  unsigned short* W1p = (unsigned short*)(w + o_W1p);
  float* w2vT   = (float*)(w + o_w2v);
  unsigned char* h1f8 = (unsigned char*)(w + o_h1f8);

  hipMemsetAsync(w, 0, zero_end, stream);

  int ebl = (E + 255) / 256;
  int nbl = (N + 255) / 256;
  int wbl = (N + 3) / 4;

  // CSR build (XCD-local atomic banks; scan2 folded into scan3)
  k_count<<<ebl, 256, 0, stream>>>(edst, eattr, degp, rank, E, N);
  k_scan1<<<nbl, 256, 0, stream>>>(degp, rowptr, bsum, N);
  k_scan3<<<nbl, 256, 0, stream>>>(rowptr, bsum, degp, lattr, base, N, E);
  k_scatter<<<ebl, 256, 0, stream>>>(esrc, edst, eattr, rank, base, csrp, E);

  // weight packing + precontracted layer-2 vectors + edge coeffs
  k_prep<<<73, 64, 0, stream>>>(W1, as1, ad1, W2, as2, ad2,
                                We1, ae1, We2, ae2, b2, Wlin, W1p, w2vT, ce);

  // layer 1 (GEMM + scores)
  k_gemm1_att<<<(N + 63) / 64, 256, 0, stream>>>(x, W1p, h1f8, asrc1, adst1, N);
  // layer-1 aggregation + fused layer-2 projection
  k_gat1<<<wbl, 256, 0, stream>>>(rowptr, csrp, lattr, asrc1, adst1, ce,
                                  h1f8, b1, w2vT, upd, N);
  // layer-2 aggregation (scalar only)
  k_gat2<<<(N + 31) / 32, 256, 0, stream>>>(rowptr, csrp, lattr, upd, ce,
                                            s1v, s2v, N);
  // pair head
  k_pairs<<<(P + 255) / 256, 256, 0, stream>>>(pairs, s1v, s2v, blin, out, P);
}

// Round 14
// 259.393 us; speedup vs baseline: 1.0700x; 1.0700x over previous
//
#include <hip/hip_runtime.h>
#include <hip/hip_fp16.h>
#include <math.h>

typedef __attribute__((ext_vector_type(8))) short short8;
typedef __attribute__((ext_vector_type(4))) float floatx4;
typedef __attribute__((ext_vector_type(2))) float float2v;

__device__ __forceinline__ unsigned short f2bf(float f){
  unsigned int x = __float_as_uint(f);
  unsigned int r = x + 0x7fff + ((x >> 16) & 1);   // RNE
  return (unsigned short)(r >> 16);
}
__device__ __forceinline__ unsigned char f2fp8(float v){
  int pk = __builtin_amdgcn_cvt_pk_fp8_f32(v, 0.f, 0, false);
  return (unsigned char)(pk & 0xff);
}
__device__ __forceinline__ float wsumf(float v){
#pragma unroll
  for (int o = 32; o; o >>= 1) v += __shfl_xor(v, o, 64);
  return v;
}

// ---------------------------------------------------------------- count: 8 XCD-local banks (bank = blockIdx&7)
__global__ __launch_bounds__(256) void k_count(const int* __restrict__ dst,
    const float* __restrict__ eattr, unsigned long long* __restrict__ degp,
    unsigned char* __restrict__ rank, int E, int N){
  int e = blockIdx.x * 256 + threadIdx.x;
  if (e >= E) return;
  int b = blockIdx.x & 7;
  int d = dst[e];
  unsigned long long add = (1ull << 40) |
      (unsigned long long)(eattr[e] * 16777216.0f);
  unsigned long long old = atomicAdd(&degp[(size_t)b * N + d], add);
  rank[e] = (unsigned char)(old >> 40);
}

// ---------------------------------------------------------------- scan1: block-local exclusive + block sums
__global__ __launch_bounds__(256) void k_scan1(const unsigned long long* __restrict__ degp,
    int* __restrict__ row_ptr, int* __restrict__ bsum, int n){
  __shared__ int sm[2][256];
  int tid = threadIdx.x, gid = blockIdx.x * 256 + tid;
  int v = 0;
  if (gid < n){
#pragma unroll
    for (int b = 0; b < 8; b++) v += (int)(degp[(size_t)b * n + gid] >> 40);
  }
  sm[0][tid] = v; __syncthreads();
  int pin = 0;
  for (int off = 1; off < 256; off <<= 1){
    int t = sm[pin][tid];
    if (tid >= off) t += sm[pin][tid - off];
    sm[pin ^ 1][tid] = t; pin ^= 1; __syncthreads();
  }
  int incl = sm[pin][tid];
  if (gid < n) row_ptr[gid] = incl - v;
  if (tid == 255) bsum[blockIdx.x] = incl;
}

// ---------------------------------------------------------------- scan3 (scan2 folded): block offset by reduction
__global__ __launch_bounds__(256) void k_scan3(int* __restrict__ row_ptr,
    const int* __restrict__ bsum, const unsigned long long* __restrict__ degp,
    float* __restrict__ lattr, int* __restrict__ base, int n, int E){
  int tid = threadIdx.x;
  int partial = (tid < (int)blockIdx.x) ? bsum[tid] : 0;   // nb <= 256
#pragma unroll
  for (int o = 32; o; o >>= 1) partial += __shfl_xor(partial, o, 64);
  __shared__ int ws[4];
  if ((tid & 63) == 0) ws[tid >> 6] = partial;
  __syncthreads();
  int blockOfs = ws[0] + ws[1] + ws[2] + ws[3];
  int gid = blockIdx.x * 256 + tid;
  if (gid >= n) return;
  int rp = row_ptr[gid] + blockOfs;
  row_ptr[gid] = rp;
  const unsigned long long M40 = (1ull << 40) - 1;
  int cum = 0; float s = 0.f;
  int bb[8];
#pragma unroll
  for (int b = 0; b < 8; b++){
    unsigned long long p = degp[(size_t)b * n + gid];
    bb[b] = rp + cum;
    cum += (int)(p >> 40);
    s += (float)(p & M40);
  }
  lattr[gid] = (s * (1.0f / 16777216.0f)) / fmaxf((float)cum, 1.0f);
  int4* bp = (int4*)(base + (size_t)gid * 8);
  bp[0] = make_int4(bb[0], bb[1], bb[2], bb[3]);
  bp[1] = make_int4(bb[4], bb[5], bb[6], bb[7]);
  if (gid == 0) row_ptr[n] = E;
}

// ---------------------------------------------------------------- scatter: CSR-ordered {src, ea} (8 B)
__global__ __launch_bounds__(256) void k_scatter(const int* __restrict__ src,
    const int* __restrict__ dst, const float* __restrict__ eattr,
    const unsigned char* __restrict__ rank, const int* __restrict__ base,
    int2* __restrict__ csr, int E){
  int e = blockIdx.x * 256 + threadIdx.x;
  if (e >= E) return;
  int b = blockIdx.x & 7;
  int d = dst[e];
  int pos = base[(size_t)d * 8 + b] + (int)rank[e];
  csr[pos] = make_int2(src[e], __float_as_int(eattr[e]));
}

// ---------------------------------------------------------------- prep: B1 tiles (17), w2vT[4][256], ce + c1/c2
__global__ void k_prep(const float* __restrict__ W1, const float* __restrict__ as1,
    const float* __restrict__ ad1, const float* __restrict__ W2,
    const float* __restrict__ as2, const float* __restrict__ ad2,
    const float* __restrict__ We1, const float* __restrict__ ae1,
    const float* __restrict__ We2, const float* __restrict__ ae2,
    const float* __restrict__ b2, const float* __restrict__ Wlin,
    unsigned short* __restrict__ W1p, float* __restrict__ w2vT,
    float* __restrict__ ce){
  int b = blockIdx.x, lane = threadIdx.x;
  if (b < 68){
    int nt = b >> 2, kc = b & 3;
    int col = lane & 15, krow = kc * 32 + (lane >> 4) * 8;
    unsigned short tmp[8];
    if (nt < 16){
#pragma unroll
      for (int j = 0; j < 8; j++) tmp[j] = f2bf(W1[(size_t)(krow + j) * 256 + nt * 16 + col]);
    } else {
#pragma unroll
      for (int j = 0; j < 8; j++){
        float v = 0.f;
        if (col < 8){
          const float* av = (col < 4) ? as1 : ad1;
          int h = col & 3;
          for (int c = 0; c < 64; c++)
            v += W1[(size_t)(krow + j) * 256 + h * 64 + c] * av[h * 64 + c];
        }
        tmp[j] = f2bf(v);
      }
    }
    unsigned short* dstp = W1p + (((size_t)nt * 4 + kc) * 64 + lane) * 8;
    *(ushort4*)(dstp)     = make_ushort4(tmp[0], tmp[1], tmp[2], tmp[3]);
    *(ushort4*)(dstp + 4) = make_ushort4(tmp[4], tmp[5], tmp[6], tmp[7]);
  } else if (b < 72){
    int k = (b - 68) * 64 + lane;
    float4 a = make_float4(0.f, 0.f, 0.f, 0.f);
    for (int c = 0; c < 64; c++){
      float wv = W2[(size_t)k * 64 + c];
      a.x += wv * as2[c];
      a.y += wv * ad2[c];
      a.z += wv * Wlin[c];
      a.w += wv * Wlin[64 + c];
    }
    w2vT[k]       = a.x;
    w2vT[256 + k] = a.y;
    w2vT[512 + k] = a.z;
    w2vT[768 + k] = a.w;
  } else {
    float p0 = We1[lane]       * ae1[lane];
    float p1 = We1[64 + lane]  * ae1[64 + lane];
    float p2 = We1[128 + lane] * ae1[128 + lane];
    float p3 = We1[192 + lane] * ae1[192 + lane];
    float p4 = We2[lane]       * ae2[lane];
    float c1 = b2[lane] * Wlin[lane];
    float c2 = b2[lane] * Wlin[64 + lane];
    p0 = wsumf(p0); p1 = wsumf(p1); p2 = wsumf(p2); p3 = wsumf(p3); p4 = wsumf(p4);
    c1 = wsumf(c1); c2 = wsumf(c2);
    if (lane == 0){
      ce[0] = p0; ce[1] = p1; ce[2] = p2; ce[3] = p3; ce[4] = p4;
      ce[5] = c1; ce[6] = c2;
    }
  }
}

// ---------------------------------------------------------------- GEMM1: fp32 A, 16 LDS tiles + reg score tile
__global__ __launch_bounds__(256) void k_gemm1_att(const float* __restrict__ A,
    const unsigned short* __restrict__ Bp, unsigned char* __restrict__ h1f8,
    float* __restrict__ asrc, float* __restrict__ adst, int M){
  constexpr int K = 128, NKC = 4;
  __shared__ unsigned short Bs[256 * K];
  {
    const uint4* srcp = (const uint4*)Bp;
    uint4* dstp = (uint4*)Bs;
    for (int i = threadIdx.x; i < 4096; i += 256) dstp[i] = srcp[i];
  }
  __syncthreads();
  int wave = threadIdx.x >> 6, lane = threadIdx.x & 63;
  int quad = lane >> 4, col = lane & 15;
  int r0 = (blockIdx.x * 4 + wave) * 16;
  int rowc = min(r0 + col, M - 1);
  short8 af[NKC], sf[NKC];
#pragma unroll
  for (int kc = 0; kc < NKC; kc++){
    float4 a0 = *(const float4*)(A + (size_t)rowc * K + kc * 32 + quad * 8);
    float4 a1 = *(const float4*)(A + (size_t)rowc * K + kc * 32 + quad * 8 + 4);
    short8 t;
    t[0] = (short)f2bf(a0.x); t[1] = (short)f2bf(a0.y);
    t[2] = (short)f2bf(a0.z); t[3] = (short)f2bf(a0.w);
    t[4] = (short)f2bf(a1.x); t[5] = (short)f2bf(a1.y);
    t[6] = (short)f2bf(a1.z); t[7] = (short)f2bf(a1.w);
    af[kc] = t;
    sf[kc] = *(const short8*)(Bp + (((size_t)16 * 4 + kc) * 64 + lane) * 8);
  }
  floatx4 acc[17];
#pragma unroll
  for (int nt = 0; nt < 17; nt++) acc[nt] = (floatx4){0.f, 0.f, 0.f, 0.f};
#pragma unroll
  for (int kc = 0; kc < NKC; kc++){
#pragma unroll
    for (int nt = 0; nt < 16; nt++){
      short8 bfv = *(const short8*)(&Bs[((nt * NKC + kc) * 64 + lane) * 8]);
      acc[nt] = __builtin_amdgcn_mfma_f32_16x16x32_bf16(af[kc], bfv, acc[nt], 0, 0, 0);
    }
    acc[16] = __builtin_amdgcn_mfma_f32_16x16x32_bf16(af[kc], sf[kc], acc[16], 0, 0, 0);
  }
#pragma unroll
  for (int nt = 0; nt < 16; nt++){
#pragma unroll
    for (int i = 0; i < 4; i++){
      int r = r0 + quad * 4 + i;
      if (r < M) h1f8[(size_t)r * 256 + nt * 16 + col] = f2fp8(acc[nt][i]);
    }
  }
#pragma unroll
  for (int i = 0; i < 4; i++){
    int r = r0 + quad * 4 + i;
    if (r < M){
      float v = acc[16][i];
      if (col < 4)      asrc[(size_t)r * 4 + col] = v;
      else if (col < 8) adst[(size_t)r * 4 + (col - 4)] = v;
    }
  }
}

// ---------------------------------------------------------------- GAT layer 1 (fused L2 projection, coalesced epilogue)
__global__ __launch_bounds__(256) void k_gat1(
    const int* __restrict__ row_ptr, const int2* __restrict__ csr,
    const float* __restrict__ lattr,
    const float* __restrict__ a_src, const float* __restrict__ a_dst,
    const float* __restrict__ ce, const unsigned char* __restrict__ hpre,
    const float* __restrict__ bias, const float* __restrict__ w2vT,
    float4* __restrict__ upd, int n){
  int node = blockIdx.x * 4 + (threadIdx.x >> 6);
  if (node >= n) return;
  int lane = threadIdx.x & 63;
  int q = lane >> 4, lsub = lane & 15, hq = lsub >> 2;
  int start = row_ptr[node], deg = row_ptr[node + 1] - start;
  float4 as4 = *(const float4*)(a_src + (size_t)node * 4);
  float4 ad4 = *(const float4*)(a_dst + (size_t)node * 4);
  float4 ce4 = *(const float4*)ce;
  float la = lattr[node];
  // loop-invariant projection weights: wave reads contiguous 4KB (lane*64B), coalesced
  float4 wv4[4];
#pragma unroll
  for (int j = 0; j < 4; j++)
    wv4[j] = *(const float4*)(w2vT + (size_t)lane * 16 + j * 4);
  float asvh = hq == 0 ? as4.x : hq == 1 ? as4.y : hq == 2 ? as4.z : as4.w;
  float advh = hq == 0 ? ad4.x : hq == 1 ? ad4.y : hq == 2 ? ad4.z : ad4.w;
  float ceh  = hq == 0 ? ce4.x : hq == 1 ? ce4.y : hq == 2 ? ce4.z : ce4.w;
  float2v acc2[8];
#pragma unroll
  for (int k = 0; k < 8; k++) acc2[k] = (float2v){0.f, 0.f};
  float dn = 0.f;
  if (q == 0){                                    // self-loop handled once
    float aself = asvh + advh + la * ceh;
    aself = aself > 0.f ? aself : 0.2f * aself;
    float wself = __expf(aself);
    dn = wself;
    uint4 u = *(const uint4*)(hpre + (size_t)node * 256 + lsub * 16);
    float2v w2 = (float2v){wself, wself};
    unsigned uu[4] = {u.x, u.y, u.z, u.w};
#pragma unroll
    for (int j = 0; j < 4; j++){
      acc2[2 * j]     = w2 * __builtin_amdgcn_cvt_pk_f32_fp8((int)uu[j], false);
      acc2[2 * j + 1] = w2 * __builtin_amdgcn_cvt_pk_f32_fp8((int)uu[j], true);
    }
  }
  for (int e = q; e < deg; e += 8){               // 2 edges per iter per quarter
    bool vB = (e + 4) < deg;
    int2 seA = csr[start + e];
    int2 seB = csr[start + (vB ? e + 4 : e)];
    float aA = a_src[(size_t)seA.x * 4 + hq] + advh + __int_as_float(seA.y) * ceh;
    aA = aA > 0.f ? aA : 0.2f * aA;
    float wA = __expf(aA);
    float aB = a_src[(size_t)seB.x * 4 + hq] + advh + __int_as_float(seB.y) * ceh;
    aB = aB > 0.f ? aB : 0.2f * aB;
    float wB = vB ? __expf(aB) : 0.f;
    uint4 uA = *(const uint4*)(hpre + (size_t)seA.x * 256 + lsub * 16);
    uint4 uB = *(const uint4*)(hpre + (size_t)seB.x * 256 + lsub * 16);
    dn += wA + wB;
    float2v wA2 = (float2v){wA, wA}, wB2 = (float2v){wB, wB};
    unsigned ua[4] = {uA.x, uA.y, uA.z, uA.w};
    unsigned ub[4] = {uB.x, uB.y, uB.z, uB.w};
#pragma unroll
    for (int j = 0; j < 4; j++){
      acc2[2 * j]     += wA2 * __builtin_amdgcn_cvt_pk_f32_fp8((int)ua[j], false);
      acc2[2 * j + 1] += wA2 * __builtin_amdgcn_cvt_pk_f32_fp8((int)ua[j], true);
      acc2[2 * j]     += wB2 * __builtin_amdgcn_cvt_pk_f32_fp8((int)ub[j], false);
      acc2[2 * j + 1] += wB2 * __builtin_amdgcn_cvt_pk_f32_fp8((int)ub[j], true);
    }
  }
  dn += __shfl_xor(dn, 16, 64);
  dn += __shfl_xor(dn, 32, 64);
#pragma unroll
  for (int k = 0; k < 8; k++){
    acc2[k].x += __shfl_xor(acc2[k].x, 16, 64);
    acc2[k].x += __shfl_xor(acc2[k].x, 32, 64);
    acc2[k].y += __shfl_xor(acc2[k].y, 16, 64);
    acc2[k].y += __shfl_xor(acc2[k].y, 32, 64);
  }
  // All-lane epilogue: quarter q computes output component q of upd[node].
  {
    float inv = 1.f / dn;
    float d = 0.f;
#pragma unroll
    for (int j = 0; j < 4; j++){
      float4 b4 = *(const float4*)(bias + lsub * 16 + j * 4);
      float bbv[4] = {b4.x, b4.y, b4.z, b4.w};
      float wvv[4] = {wv4[j].x, wv4[j].y, wv4[j].z, wv4[j].w};
#pragma unroll
      for (int t = 0; t < 4; t++){
        int k = j * 4 + t;
        float av = (k & 1) ? acc2[k >> 1].y : acc2[k >> 1].x;
        float v = av * inv + bbv[t];
        v = v > 0.f ? v : (__expf(v) - 1.f);    // elu(h1)
        d += v * wvv[t];
      }
    }
#pragma unroll
    for (int o = 1; o < 16; o <<= 1) d += __shfl_xor(d, o, 64);
    if (lsub == 0) ((float*)&upd[node])[q] = d;
  }
}

// ---------------------------------------------------------------- GAT layer 2: scalar-only (8 lanes per node)
__global__ __launch_bounds__(256) void k_gat2(
    const int* __restrict__ row_ptr, const int2* __restrict__ csr,
    const float* __restrict__ lattr, const float4* __restrict__ upd,
    const float* __restrict__ ce,
    float* __restrict__ s1v, float* __restrict__ s2v, int n){
  int node = blockIdx.x * 32 + (threadIdx.x >> 3);
  if (node >= n) return;
  int lane8 = threadIdx.x & 7;
  int start = row_ptr[node], deg = row_ptr[node + 1] - start;
  float4 own = upd[node];
  float ad = own.y, c = ce[4];
  float t1 = 0.f, t2 = 0.f, dn = 0.f;
  if (lane8 == 0){
    float a = own.x + ad + lattr[node] * c;
    a = a > 0.f ? a : 0.2f * a;
    float w = __expf(a);
    dn = w; t1 = w * own.z; t2 = w * own.w;
  }
  for (int e = lane8; e < deg; e += 8){
    int2 se = csr[start + e];
    float4 o = upd[se.x];
    float a = o.x + ad + __int_as_float(se.y) * c;
    a = a > 0.f ? a : 0.2f * a;
    float w = __expf(a);
    dn += w; t1 += w * o.z; t2 += w * o.w;
  }
#pragma unroll
  for (int o = 1; o < 8; o <<= 1){
    dn += __shfl_xor(dn, o, 64);
    t1 += __shfl_xor(t1, o, 64);
    t2 += __shfl_xor(t2, o, 64);
  }
  if (lane8 == 0){
    float inv = 1.f / dn;
    s1v[node] = t1 * inv + ce[5];
    s2v[node] = t2 * inv + ce[6];
  }
}

// ---------------------------------------------------------------- pair head
__global__ __launch_bounds__(256) void k_pairs(const int* __restrict__ pairs,
    const float* __restrict__ s1v, const float* __restrict__ s2v,
    const float* __restrict__ blin, float* __restrict__ out, int P){
  int p = blockIdx.x * 256 + threadIdx.x;
  if (p >= P) return;
  int i = pairs[2 * p], j = pairs[2 * p + 1];
  float x = s1v[i] + s2v[j] + blin[0];
  out[p] = 1.f / (1.f + __expf(-x));
}

// ---------------------------------------------------------------- launch
extern "C" void kernel_launch(void* const* d_in, const int* in_sizes, int n_in,
                              void* d_out, int out_size, void* d_ws, size_t ws_size,
                              hipStream_t stream) {
  const float* x     = (const float*)d_in[0];
  const int*   esrc  = (const int*)  d_in[1];
  const int*   edst  = (const int*)  d_in[2];
  const float* eattr = (const float*)d_in[3];
  const int*   pairs = (const int*)  d_in[4];
  const float* W1    = (const float*)d_in[5];
  const float* We1   = (const float*)d_in[6];
  const float* as1   = (const float*)d_in[7];
  const float* ad1   = (const float*)d_in[8];
  const float* ae1   = (const float*)d_in[9];
  const float* b1    = (const float*)d_in[10];
  const float* W2    = (const float*)d_in[11];
  const float* We2   = (const float*)d_in[12];
  const float* as2   = (const float*)d_in[13];
  const float* ad2   = (const float*)d_in[14];
  const float* ae2   = (const float*)d_in[15];
  const float* b2    = (const float*)d_in[16];
  const float* Wlin  = (const float*)d_in[17];
  const float* blin  = (const float*)d_in[18];
  float* out = (float*)d_out;

  const int N = in_sizes[0] / 128;
  const int E = in_sizes[1];
  const int P = in_sizes[4] / 2;

  char* w = (char*)d_ws;
  size_t off = 0;
  auto alloc = [&](size_t bytes) -> size_t {
    size_t r = off; off = (off + bytes + 255) & ~(size_t)255; return r;
  };
  size_t o_degp   = alloc((size_t)N * 64);   // 8 banks of u64
  size_t zero_end = off;
  size_t o_rank   = alloc((size_t)E);        // uint8 rank
  size_t o_rowptr = alloc((size_t)(N + 1) * 4);
  size_t o_bsum   = alloc(1024);
  size_t o_lattr  = alloc((size_t)N * 4);
  size_t o_base   = alloc((size_t)N * 32);
  size_t o_csr    = alloc((size_t)E * 8);    // int2 {src, ea}
  size_t o_asrc1  = alloc((size_t)N * 16);
  size_t o_adst1  = alloc((size_t)N * 16);
  size_t o_upd    = alloc((size_t)N * 16);
  size_t o_ce     = alloc(64);
  size_t o_s1     = alloc((size_t)N * 4);
  size_t o_s2     = alloc((size_t)N * 4);
  size_t o_W1p    = alloc((size_t)17 * 4 * 64 * 8 * 2);
  size_t o_w2v    = alloc(256 * 16);         // w2vT[4][256] floats
  size_t o_h1f8   = alloc((size_t)N * 256);
  (void)ws_size;

  unsigned long long* degp = (unsigned long long*)(w + o_degp);
  unsigned char* rank = (unsigned char*)(w + o_rank);
  int*   rowptr = (int*)  (w + o_rowptr);
  int*   bsum   = (int*)  (w + o_bsum);
  float* lattr  = (float*)(w + o_lattr);
  int*   base   = (int*)  (w + o_base);
  int2*  csr    = (int2*) (w + o_csr);
  float* asrc1  = (float*)(w + o_asrc1);
  float* adst1  = (float*)(w + o_adst1);
  float4* upd   = (float4*)(w + o_upd);
  float* ce     = (float*)(w + o_ce);
  float* s1v    = (float*)(w + o_s1);
  float* s2v    = (float*)(w + o_s2);
  unsigned short* W1p = (unsigned short*)(w + o_W1p);
  float* w2vT   = (float*)(w + o_w2v);
  unsigned char* h1f8 = (unsigned char*)(w + o_h1f8);

  hipMemsetAsync(w, 0, zero_end, stream);

  int ebl = (E + 255) / 256;
  int nbl = (N + 255) / 256;
  int wbl = (N + 3) / 4;

  // CSR build (XCD-local atomic banks; scan2 folded into scan3)
  k_count<<<ebl, 256, 0, stream>>>(edst, eattr, degp, rank, E, N);
  k_scan1<<<nbl, 256, 0, stream>>>(degp, rowptr, bsum, N);
  k_scan3<<<nbl, 256, 0, stream>>>(rowptr, bsum, degp, lattr, base, N, E);
  k_scatter<<<ebl, 256, 0, stream>>>(esrc, edst, eattr, rank, base, csr, E);

  // weight packing + precontracted layer-2 vectors + edge coeffs
  k_prep<<<73, 64, 0, stream>>>(W1, as1, ad1, W2, as2, ad2,
                                We1, ae1, We2, ae2, b2, Wlin, W1p, w2vT, ce);

  // layer 1 (GEMM + scores)
  k_gemm1_att<<<(N + 63) / 64, 256, 0, stream>>>(x, W1p, h1f8, asrc1, adst1, N);
  // layer-1 aggregation + fused layer-2 projection
  k_gat1<<<wbl, 256, 0, stream>>>(rowptr, csr, lattr, asrc1, adst1, ce,
                                  h1f8, b1, w2vT, upd, N);
  // layer-2 aggregation (scalar only)
  k_gat2<<<(N + 31) / 32, 256, 0, stream>>>(rowptr, csr, lattr, upd, ce,
                                            s1v, s2v, N);
  // pair head
  k_pairs<<<(P + 255) / 256, 256, 0, stream>>>(pairs, s1v, s2v, blin, out, P);
}

// Round 15
// 255.514 us; speedup vs baseline: 1.0862x; 1.0152x over previous
//
#include <hip/hip_runtime.h>
#include <hip/hip_fp16.h>
#include <math.h>

typedef __attribute__((ext_vector_type(8))) short short8;
typedef __attribute__((ext_vector_type(4))) float floatx4;
typedef __attribute__((ext_vector_type(2))) float float2v;

__device__ __forceinline__ unsigned short f2bf(float f){
  unsigned int x = __float_as_uint(f);
  unsigned int r = x + 0x7fff + ((x >> 16) & 1);   // RNE
  return (unsigned short)(r >> 16);
}
__device__ __forceinline__ unsigned char f2fp8(float v){
  int pk = __builtin_amdgcn_cvt_pk_fp8_f32(v, 0.f, 0, false);
  return (unsigned char)(pk & 0xff);
}
__device__ __forceinline__ float wsumf(float v){
#pragma unroll
  for (int o = 32; o; o >>= 1) v += __shfl_xor(v, o, 64);
  return v;
}

// ---------------------------------------------------------------- count: 8 XCD-local u32 banks, 2 edges/thread
// degp[b*N+d]: bits[31:24]=count, [23:0]=sum(eattr)*2^18. bank(e) = (e>>8)&7.
__global__ __launch_bounds__(256) void k_count(const int* __restrict__ dst,
    const float* __restrict__ eattr, unsigned* __restrict__ degp,
    unsigned char* __restrict__ rank, int E, int N){
  int e0 = blockIdx.x * 512 + threadIdx.x;
  int e1 = e0 + 256;
  bool v0 = e0 < E, v1 = e1 < E;
  int d0 = 0, d1 = 0; float a0 = 0.f, a1 = 0.f;
  if (v0){ d0 = dst[e0]; a0 = eattr[e0]; }
  if (v1){ d1 = dst[e1]; a1 = eattr[e1]; }
  int b0 = (e0 >> 8) & 7, b1 = (e1 >> 8) & 7;
  if (v0){
    unsigned old = atomicAdd(&degp[(size_t)b0 * N + d0],
                             (1u << 24) | (unsigned)(a0 * 262144.0f));
    rank[e0] = (unsigned char)(old >> 24);
  }
  if (v1){
    unsigned old = atomicAdd(&degp[(size_t)b1 * N + d1],
                             (1u << 24) | (unsigned)(a1 * 262144.0f));
    rank[e1] = (unsigned char)(old >> 24);
  }
}

// ---------------------------------------------------------------- scan1: block-local exclusive + block sums
__global__ __launch_bounds__(256) void k_scan1(const unsigned* __restrict__ degp,
    int* __restrict__ row_ptr, int* __restrict__ bsum, int n){
  __shared__ int sm[2][256];
  int tid = threadIdx.x, gid = blockIdx.x * 256 + tid;
  int v = 0;
  if (gid < n){
#pragma unroll
    for (int b = 0; b < 8; b++) v += (int)(degp[(size_t)b * n + gid] >> 24);
  }
  sm[0][tid] = v; __syncthreads();
  int pin = 0;
  for (int off = 1; off < 256; off <<= 1){
    int t = sm[pin][tid];
    if (tid >= off) t += sm[pin][tid - off];
    sm[pin ^ 1][tid] = t; pin ^= 1; __syncthreads();
  }
  int incl = sm[pin][tid];
  if (gid < n) row_ptr[gid] = incl - v;
  if (tid == 255) bsum[blockIdx.x] = incl;
}

// ---------------------------------------------------------------- scan3 (scan2 folded): block offset by reduction
__global__ __launch_bounds__(256) void k_scan3(int* __restrict__ row_ptr,
    const int* __restrict__ bsum, const unsigned* __restrict__ degp,
    float* __restrict__ lattr, int* __restrict__ base, int n, int E){
  int tid = threadIdx.x;
  int partial = (tid < (int)blockIdx.x) ? bsum[tid] : 0;   // nb <= 256
#pragma unroll
  for (int o = 32; o; o >>= 1) partial += __shfl_xor(partial, o, 64);
  __shared__ int ws[4];
  if ((tid & 63) == 0) ws[tid >> 6] = partial;
  __syncthreads();
  int blockOfs = ws[0] + ws[1] + ws[2] + ws[3];
  int gid = blockIdx.x * 256 + tid;
  if (gid >= n) return;
  int rp = row_ptr[gid] + blockOfs;
  row_ptr[gid] = rp;
  int cum = 0; float s = 0.f;
  int bb[8];
#pragma unroll
  for (int b = 0; b < 8; b++){
    unsigned p = degp[(size_t)b * n + gid];
    bb[b] = rp + cum;
    cum += (int)(p >> 24);
    s += (float)(p & 0xffffffu);
  }
  lattr[gid] = (s * (1.0f / 262144.0f)) / fmaxf((float)cum, 1.0f);
  int4* bp = (int4*)(base + (size_t)gid * 8);
  bp[0] = make_int4(bb[0], bb[1], bb[2], bb[3]);
  bp[1] = make_int4(bb[4], bb[5], bb[6], bb[7]);
  if (gid == 0) row_ptr[n] = E;
}

// ---------------------------------------------------------------- scatter: CSR-ordered {src, ea}, 2 edges/thread
__global__ __launch_bounds__(256) void k_scatter(const int* __restrict__ src,
    const int* __restrict__ dst, const float* __restrict__ eattr,
    const unsigned char* __restrict__ rank, const int* __restrict__ base,
    int2* __restrict__ csr, int E){
  int e0 = blockIdx.x * 512 + threadIdx.x;
  int e1 = e0 + 256;
  bool v0 = e0 < E, v1 = e1 < E;
  int b0 = (e0 >> 8) & 7, b1 = (e1 >> 8) & 7;
  if (v0){
    int d = dst[e0];
    int pos = base[(size_t)d * 8 + b0] + (int)rank[e0];
    csr[pos] = make_int2(src[e0], __float_as_int(eattr[e0]));
  }
  if (v1){
    int d = dst[e1];
    int pos = base[(size_t)d * 8 + b1] + (int)rank[e1];
    csr[pos] = make_int2(src[e1], __float_as_int(eattr[e1]));
  }
}

// ---------------------------------------------------------------- prep: B1 tiles (17), w2vT[4][256], ce + c1/c2
__global__ void k_prep(const float* __restrict__ W1, const float* __restrict__ as1,
    const float* __restrict__ ad1, const float* __restrict__ W2,
    const float* __restrict__ as2, const float* __restrict__ ad2,
    const float* __restrict__ We1, const float* __restrict__ ae1,
    const float* __restrict__ We2, const float* __restrict__ ae2,
    const float* __restrict__ b2, const float* __restrict__ Wlin,
    unsigned short* __restrict__ W1p, float* __restrict__ w2vT,
    float* __restrict__ ce){
  int b = blockIdx.x, lane = threadIdx.x;
  if (b < 68){
    int nt = b >> 2, kc = b & 3;
    int col = lane & 15, krow = kc * 32 + (lane >> 4) * 8;
    unsigned short tmp[8];
    if (nt < 16){
#pragma unroll
      for (int j = 0; j < 8; j++) tmp[j] = f2bf(W1[(size_t)(krow + j) * 256 + nt * 16 + col]);
    } else {
#pragma unroll
      for (int j = 0; j < 8; j++){
        float v = 0.f;
        if (col < 8){
          const float* av = (col < 4) ? as1 : ad1;
          int h = col & 3;
          for (int c = 0; c < 64; c++)
            v += W1[(size_t)(krow + j) * 256 + h * 64 + c] * av[h * 64 + c];
        }
        tmp[j] = f2bf(v);
      }
    }
    unsigned short* dstp = W1p + (((size_t)nt * 4 + kc) * 64 + lane) * 8;
    *(ushort4*)(dstp)     = make_ushort4(tmp[0], tmp[1], tmp[2], tmp[3]);
    *(ushort4*)(dstp + 4) = make_ushort4(tmp[4], tmp[5], tmp[6], tmp[7]);
  } else if (b < 72){
    int k = (b - 68) * 64 + lane;
    float4 a = make_float4(0.f, 0.f, 0.f, 0.f);
    for (int c = 0; c < 64; c++){
      float wv = W2[(size_t)k * 64 + c];
      a.x += wv * as2[c];
      a.y += wv * ad2[c];
      a.z += wv * Wlin[c];
      a.w += wv * Wlin[64 + c];
    }
    w2vT[k]       = a.x;
    w2vT[256 + k] = a.y;
    w2vT[512 + k] = a.z;
    w2vT[768 + k] = a.w;
  } else {
    float p0 = We1[lane]       * ae1[lane];
    float p1 = We1[64 + lane]  * ae1[64 + lane];
    float p2 = We1[128 + lane] * ae1[128 + lane];
    float p3 = We1[192 + lane] * ae1[192 + lane];
    float p4 = We2[lane]       * ae2[lane];
    float c1 = b2[lane] * Wlin[lane];
    float c2 = b2[lane] * Wlin[64 + lane];
    p0 = wsumf(p0); p1 = wsumf(p1); p2 = wsumf(p2); p3 = wsumf(p3); p4 = wsumf(p4);
    c1 = wsumf(c1); c2 = wsumf(c2);
    if (lane == 0){
      ce[0] = p0; ce[1] = p1; ce[2] = p2; ce[3] = p3; ce[4] = p4;
      ce[5] = c1; ce[6] = c2;
    }
  }
}

// ---------------------------------------------------------------- GEMM1: fp32 A, 16 LDS tiles + reg score tile
__global__ __launch_bounds__(256) void k_gemm1_att(const float* __restrict__ A,
    const unsigned short* __restrict__ Bp, unsigned char* __restrict__ h1f8,
    float* __restrict__ asrc, float* __restrict__ adst, int M){
  constexpr int K = 128, NKC = 4;
  __shared__ unsigned short Bs[256 * K];
  {
    const uint4* srcp = (const uint4*)Bp;
    uint4* dstp = (uint4*)Bs;
    for (int i = threadIdx.x; i < 4096; i += 256) dstp[i] = srcp[i];
  }
  __syncthreads();
  int wave = threadIdx.x >> 6, lane = threadIdx.x & 63;
  int quad = lane >> 4, col = lane & 15;
  int r0 = (blockIdx.x * 4 + wave) * 16;
  int rowc = min(r0 + col, M - 1);
  short8 af[NKC], sf[NKC];
#pragma unroll
  for (int kc = 0; kc < NKC; kc++){
    float4 a0 = *(const float4*)(A + (size_t)rowc * K + kc * 32 + quad * 8);
    float4 a1 = *(const float4*)(A + (size_t)rowc * K + kc * 32 + quad * 8 + 4);
    short8 t;
    t[0] = (short)f2bf(a0.x); t[1] = (short)f2bf(a0.y);
    t[2] = (short)f2bf(a0.z); t[3] = (short)f2bf(a0.w);
    t[4] = (short)f2bf(a1.x); t[5] = (short)f2bf(a1.y);
    t[6] = (short)f2bf(a1.z); t[7] = (short)f2bf(a1.w);
    af[kc] = t;
    sf[kc] = *(const short8*)(Bp + (((size_t)16 * 4 + kc) * 64 + lane) * 8);
  }
  floatx4 acc[17];
#pragma unroll
  for (int nt = 0; nt < 17; nt++) acc[nt] = (floatx4){0.f, 0.f, 0.f, 0.f};
#pragma unroll
  for (int kc = 0; kc < NKC; kc++){
#pragma unroll
    for (int nt = 0; nt < 16; nt++){
      short8 bfv = *(const short8*)(&Bs[((nt * NKC + kc) * 64 + lane) * 8]);
      acc[nt] = __builtin_amdgcn_mfma_f32_16x16x32_bf16(af[kc], bfv, acc[nt], 0, 0, 0);
    }
    acc[16] = __builtin_amdgcn_mfma_f32_16x16x32_bf16(af[kc], sf[kc], acc[16], 0, 0, 0);
  }
#pragma unroll
  for (int nt = 0; nt < 16; nt++){
#pragma unroll
    for (int i = 0; i < 4; i++){
      int r = r0 + quad * 4 + i;
      if (r < M) h1f8[(size_t)r * 256 + nt * 16 + col] = f2fp8(acc[nt][i]);
    }
  }
#pragma unroll
  for (int i = 0; i < 4; i++){
    int r = r0 + quad * 4 + i;
    if (r < M){
      float v = acc[16][i];
      if (col < 4)      asrc[(size_t)r * 4 + col] = v;
      else if (col < 8) adst[(size_t)r * 4 + (col - 4)] = v;
    }
  }
}

// ---------------------------------------------------------------- GAT layer 1 (fused L2 projection, coalesced epilogue)
__global__ __launch_bounds__(256) void k_gat1(
    const int* __restrict__ row_ptr, const int2* __restrict__ csr,
    const float* __restrict__ lattr,
    const float* __restrict__ a_src, const float* __restrict__ a_dst,
    const float* __restrict__ ce, const unsigned char* __restrict__ hpre,
    const float* __restrict__ bias, const float* __restrict__ w2vT,
    float4* __restrict__ upd, int n){
  int node = blockIdx.x * 4 + (threadIdx.x >> 6);
  if (node >= n) return;
  int lane = threadIdx.x & 63;
  int q = lane >> 4, lsub = lane & 15, hq = lsub >> 2;
  int start = row_ptr[node], deg = row_ptr[node + 1] - start;
  float4 as4 = *(const float4*)(a_src + (size_t)node * 4);
  float4 ad4 = *(const float4*)(a_dst + (size_t)node * 4);
  float4 ce4 = *(const float4*)ce;
  float la = lattr[node];
  // loop-invariant projection weights: wave reads contiguous 4KB (lane*64B), coalesced
  float4 wv4[4];
#pragma unroll
  for (int j = 0; j < 4; j++)
    wv4[j] = *(const float4*)(w2vT + (size_t)lane * 16 + j * 4);
  float asvh = hq == 0 ? as4.x : hq == 1 ? as4.y : hq == 2 ? as4.z : as4.w;
  float advh = hq == 0 ? ad4.x : hq == 1 ? ad4.y : hq == 2 ? ad4.z : ad4.w;
  float ceh  = hq == 0 ? ce4.x : hq == 1 ? ce4.y : hq == 2 ? ce4.z : ce4.w;
  float2v acc2[8];
#pragma unroll
  for (int k = 0; k < 8; k++) acc2[k] = (float2v){0.f, 0.f};
  float dn = 0.f;
  if (q == 0){                                    // self-loop handled once
    float aself = asvh + advh + la * ceh;
    aself = aself > 0.f ? aself : 0.2f * aself;
    float wself = __expf(aself);
    dn = wself;
    uint4 u = *(const uint4*)(hpre + (size_t)node * 256 + lsub * 16);
    float2v w2 = (float2v){wself, wself};
    unsigned uu[4] = {u.x, u.y, u.z, u.w};
#pragma unroll
    for (int j = 0; j < 4; j++){
      acc2[2 * j]     = w2 * __builtin_amdgcn_cvt_pk_f32_fp8((int)uu[j], false);
      acc2[2 * j + 1] = w2 * __builtin_amdgcn_cvt_pk_f32_fp8((int)uu[j], true);
    }
  }
  for (int e = q; e < deg; e += 8){               // 2 edges per iter per quarter
    bool vB = (e + 4) < deg;
    int2 seA = csr[start + e];
    int2 seB = csr[start + (vB ? e + 4 : e)];
    float aA = a_src[(size_t)seA.x * 4 + hq] + advh + __int_as_float(seA.y) * ceh;
    aA = aA > 0.f ? aA : 0.2f * aA;
    float wA = __expf(aA);
    float aB = a_src[(size_t)seB.x * 4 + hq] + advh + __int_as_float(seB.y) * ceh;
    aB = aB > 0.f ? aB : 0.2f * aB;
    float wB = vB ? __expf(aB) : 0.f;
    uint4 uA = *(const uint4*)(hpre + (size_t)seA.x * 256 + lsub * 16);
    uint4 uB = *(const uint4*)(hpre + (size_t)seB.x * 256 + lsub * 16);
    dn += wA + wB;
    float2v wA2 = (float2v){wA, wA}, wB2 = (float2v){wB, wB};
    unsigned ua[4] = {uA.x, uA.y, uA.z, uA.w};
    unsigned ub[4] = {uB.x, uB.y, uB.z, uB.w};
#pragma unroll
    for (int j = 0; j < 4; j++){
      acc2[2 * j]     += wA2 * __builtin_amdgcn_cvt_pk_f32_fp8((int)ua[j], false);
      acc2[2 * j + 1] += wA2 * __builtin_amdgcn_cvt_pk_f32_fp8((int)ua[j], true);
      acc2[2 * j]     += wB2 * __builtin_amdgcn_cvt_pk_f32_fp8((int)ub[j], false);
      acc2[2 * j + 1] += wB2 * __builtin_amdgcn_cvt_pk_f32_fp8((int)ub[j], true);
    }
  }
  dn += __shfl_xor(dn, 16, 64);
  dn += __shfl_xor(dn, 32, 64);
#pragma unroll
  for (int k = 0; k < 8; k++){
    acc2[k].x += __shfl_xor(acc2[k].x, 16, 64);
    acc2[k].x += __shfl_xor(acc2[k].x, 32, 64);
    acc2[k].y += __shfl_xor(acc2[k].y, 16, 64);
    acc2[k].y += __shfl_xor(acc2[k].y, 32, 64);
  }
  // All-lane epilogue: quarter q computes output component q of upd[node].
  {
    float inv = 1.f / dn;
    float d = 0.f;
#pragma unroll
    for (int j = 0; j < 4; j++){
      float4 b4 = *(const float4*)(bias + lsub * 16 + j * 4);
      float bbv[4] = {b4.x, b4.y, b4.z, b4.w};
      float wvv[4] = {wv4[j].x, wv4[j].y, wv4[j].z, wv4[j].w};
#pragma unroll
      for (int t = 0; t < 4; t++){
        int k = j * 4 + t;
        float av = (k & 1) ? acc2[k >> 1].y : acc2[k >> 1].x;
        float v = av * inv + bbv[t];
        v = v > 0.f ? v : (__expf(v) - 1.f);    // elu(h1)
        d += v * wvv[t];
      }
    }
#pragma unroll
    for (int o = 1; o < 16; o <<= 1) d += __shfl_xor(d, o, 64);
    if (lsub == 0) ((float*)&upd[node])[q] = d;
  }
}

// ---------------------------------------------------------------- GAT layer 2: scalar-only (8 lanes per node)
__global__ __launch_bounds__(256) void k_gat2(
    const int* __restrict__ row_ptr, const int2* __restrict__ csr,
    const float* __restrict__ lattr, const float4* __restrict__ upd,
    const float* __restrict__ ce,
    float* __restrict__ s1v, float* __restrict__ s2v, int n){
  int node = blockIdx.x * 32 + (threadIdx.x >> 3);
  if (node >= n) return;
  int lane8 = threadIdx.x & 7;
  int start = row_ptr[node], deg = row_ptr[node + 1] - start;
  float4 own = upd[node];
  float ad = own.y, c = ce[4];
  float t1 = 0.f, t2 = 0.f, dn = 0.f;
  if (lane8 == 0){
    float a = own.x + ad + lattr[node] * c;
    a = a > 0.f ? a : 0.2f * a;
    float w = __expf(a);
    dn = w; t1 = w * own.z; t2 = w * own.w;
  }
  for (int e = lane8; e < deg; e += 8){
    int2 se = csr[start + e];
    float4 o = upd[se.x];
    float a = o.x + ad + __int_as_float(se.y) * c;
    a = a > 0.f ? a : 0.2f * a;
    float w = __expf(a);
    dn += w; t1 += w * o.z; t2 += w * o.w;
  }
#pragma unroll
  for (int o = 1; o < 8; o <<= 1){
    dn += __shfl_xor(dn, o, 64);
    t1 += __shfl_xor(t1, o, 64);
    t2 += __shfl_xor(t2, o, 64);
  }
  if (lane8 == 0){
    float inv = 1.f / dn;
    s1v[node] = t1 * inv + ce[5];
    s2v[node] = t2 * inv + ce[6];
  }
}

// ---------------------------------------------------------------- pair head
__global__ __launch_bounds__(256) void k_pairs(const int* __restrict__ pairs,
    const float* __restrict__ s1v, const float* __restrict__ s2v,
    const float* __restrict__ blin, float* __restrict__ out, int P){
  int p = blockIdx.x * 256 + threadIdx.x;
  if (p >= P) return;
  int i = pairs[2 * p], j = pairs[2 * p + 1];
  float x = s1v[i] + s2v[j] + blin[0];
  out[p] = 1.f / (1.f + __expf(-x));
}

// ---------------------------------------------------------------- launch
extern "C" void kernel_launch(void* const* d_in, const int* in_sizes, int n_in,
                              void* d_out, int out_size, void* d_ws, size_t ws_size,
                              hipStream_t stream) {
  const float* x     = (const float*)d_in[0];
  const int*   esrc  = (const int*)  d_in[1];
  const int*   edst  = (const int*)  d_in[2];
  const float* eattr = (const float*)d_in[3];
  const int*   pairs = (const int*)  d_in[4];
  const float* W1    = (const float*)d_in[5];
  const float* We1   = (const float*)d_in[6];
  const float* as1   = (const float*)d_in[7];
  const float* ad1   = (const float*)d_in[8];
  const float* ae1   = (const float*)d_in[9];
  const float* b1    = (const float*)d_in[10];
  const float* W2    = (const float*)d_in[11];
  const float* We2   = (const float*)d_in[12];
  const float* as2   = (const float*)d_in[13];
  const float* ad2   = (const float*)d_in[14];
  const float* ae2   = (const float*)d_in[15];
  const float* b2    = (const float*)d_in[16];
  const float* Wlin  = (const float*)d_in[17];
  const float* blin  = (const float*)d_in[18];
  float* out = (float*)d_out;

  const int N = in_sizes[0] / 128;
  const int E = in_sizes[1];
  const int P = in_sizes[4] / 2;

  char* w = (char*)d_ws;
  size_t off = 0;
  auto alloc = [&](size_t bytes) -> size_t {
    size_t r = off; off = (off + bytes + 255) & ~(size_t)255; return r;
  };
  size_t o_degp   = alloc((size_t)N * 32);   // 8 banks of u32
  size_t zero_end = off;
  size_t o_rank   = alloc((size_t)E);        // uint8 rank
  size_t o_rowptr = alloc((size_t)(N + 1) * 4);
  size_t o_bsum   = alloc(1024);
  size_t o_lattr  = alloc((size_t)N * 4);
  size_t o_base   = alloc((size_t)N * 32);
  size_t o_csr    = alloc((size_t)E * 8);    // int2 {src, ea}
  size_t o_asrc1  = alloc((size_t)N * 16);
  size_t o_adst1  = alloc((size_t)N * 16);
  size_t o_upd    = alloc((size_t)N * 16);
  size_t o_ce     = alloc(64);
  size_t o_s1     = alloc((size_t)N * 4);
  size_t o_s2     = alloc((size_t)N * 4);
  size_t o_W1p    = alloc((size_t)17 * 4 * 64 * 8 * 2);
  size_t o_w2v    = alloc(256 * 16);         // w2vT[4][256] floats
  size_t o_h1f8   = alloc((size_t)N * 256);
  (void)ws_size;

  unsigned* degp = (unsigned*)(w + o_degp);
  unsigned char* rank = (unsigned char*)(w + o_rank);
  int*   rowptr = (int*)  (w + o_rowptr);
  int*   bsum   = (int*)  (w + o_bsum);
  float* lattr  = (float*)(w + o_lattr);
  int*   base   = (int*)  (w + o_base);
  int2*  csr    = (int2*) (w + o_csr);
  float* asrc1  = (float*)(w + o_asrc1);
  float* adst1  = (float*)(w + o_adst1);
  float4* upd   = (float4*)(w + o_upd);
  float* ce     = (float*)(w + o_ce);
  float* s1v    = (float*)(w + o_s1);
  float* s2v    = (float*)(w + o_s2);
  unsigned short* W1p = (unsigned short*)(w + o_W1p);
  float* w2vT   = (float*)(w + o_w2v);
  unsigned char* h1f8 = (unsigned char*)(w + o_h1f8);

  hipMemsetAsync(w, 0, zero_end, stream);

  int ebl2 = (E + 511) / 512;    // 2 edges/thread kernels
  int nbl = (N + 255) / 256;
  int wbl = (N + 3) / 4;

  // CSR build (XCD-local u32 atomic banks; 2-edge ILP; scan2 folded into scan3)
  k_count<<<ebl2, 256, 0, stream>>>(edst, eattr, degp, rank, E, N);
  k_scan1<<<nbl, 256, 0, stream>>>(degp, rowptr, bsum, N);
  k_scan3<<<nbl, 256, 0, stream>>>(rowptr, bsum, degp, lattr, base, N, E);
  k_scatter<<<ebl2, 256, 0, stream>>>(esrc, edst, eattr, rank, base, csr, E);

  // weight packing + precontracted layer-2 vectors + edge coeffs
  k_prep<<<73, 64, 0, stream>>>(W1, as1, ad1, W2, as2, ad2,
                                We1, ae1, We2, ae2, b2, Wlin, W1p, w2vT, ce);

  // layer 1 (GEMM + scores)
  k_gemm1_att<<<(N + 63) / 64, 256, 0, stream>>>(x, W1p, h1f8, asrc1, adst1, N);
  // layer-1 aggregation + fused layer-2 projection
  k_gat1<<<wbl, 256, 0, stream>>>(rowptr, csr, lattr, asrc1, adst1, ce,
                                  h1f8, b1, w2vT, upd, N);
  // layer-2 aggregation (scalar only)
  k_gat2<<<(N + 31) / 32, 256, 0, stream>>>(rowptr, csr, lattr, upd, ce,
                                            s1v, s2v, N);
  // pair head
  k_pairs<<<(P + 255) / 256, 256, 0, stream>>>(pairs, s1v, s2v, blin, out, P);
}